// Round 1
// baseline (2995.635 us; speedup 1.0000x reference)
//
#include <hip/hip_runtime.h>
#include <cstdint>
#include <cstddef>

#define BATCH 64
#define SEQ   128
#define EMB   512
#define HID   1024
#define NCLS  10000
#define NG    4096      // 4*HID gate columns
#define NOP   10048     // padded output columns (314 * 32)

typedef __attribute__((ext_vector_type(8))) short short8;
typedef __attribute__((ext_vector_type(4))) short short4v;
typedef __attribute__((ext_vector_type(4))) float floatx4;
typedef unsigned short u16;

__device__ __forceinline__ u16 f2bf(float x) {
    union { float f; unsigned u; } v; v.f = x;
    unsigned r = v.u + 0x7fffu + ((v.u >> 16) & 1u);   // RNE
    return (u16)(r >> 16);
}
__device__ __forceinline__ float sigm(float x) { return 1.f / (1.f + __expf(-x)); }

// ---------------------------------------------------------------------------
// Pack 4 gate matrices [K][1024] fp32 -> Wcat k-inner-8 bf16 layout:
//   element (k, col n) at dst[((k>>3)*NG + n)*8 + (k&7)],  n = unit*4 + gate.
// Thread handles one (kgroup, unit): 4 gates * 8 k = 64 B contiguous write.
// ---------------------------------------------------------------------------
__global__ void pack_gates(const float* __restrict__ s0, const float* __restrict__ s1,
                           const float* __restrict__ s2, const float* __restrict__ s3,
                           u16* __restrict__ dst, int kgroups, int kg_off) {
    int t = blockIdx.x * blockDim.x + threadIdx.x;
    if (t >= kgroups * HID) return;
    int u  = t & (HID - 1);
    int kg = t >> 10;
    u16* out = dst + ((size_t)(kg + kg_off) * NG + (size_t)u * 4) * 8;
#pragma unroll
    for (int g = 0; g < 4; ++g) {
        const float* s = (g == 0) ? s0 : (g == 1) ? s1 : (g == 2) ? s2 : s3;
        short8 v;
#pragma unroll
        for (int j = 0; j < 8; ++j)
            v[j] = (short)f2bf(s[(size_t)(kg * 8 + j) * HID + u]);
        *(short8*)(out + g * 8) = v;
    }
}

// W_out [1024][10000] fp32 -> padded k-inner-8 bf16 [(128)][10048][8]
__global__ void pack_wout(const float* __restrict__ src, u16* __restrict__ dst) {
    int t = blockIdx.x * blockDim.x + threadIdx.x;
    if (t >= 128 * NCLS) return;
    int n  = t % NCLS;
    int kg = t / NCLS;
    short8 v;
#pragma unroll
    for (int j = 0; j < 8; ++j)
        v[j] = (short)f2bf(src[(size_t)(kg * 8 + j) * NCLS + n]);
    *(short8*)(dst + ((size_t)kg * NOP + n) * 8) = v;
}

// E[s][b][:] = bf16(C[X[b][s]][:])   (E laid out [SEQ][BATCH][EMB])
__global__ void embed_k(const int* __restrict__ X, const float* __restrict__ C,
                        u16* __restrict__ E) {
    const int sb = blockIdx.x;             // s*64 + m
    const int s = sb >> 6, m = sb & 63;
    const int row = X[m * SEQ + s];
    const floatx4* src = (const floatx4*)(C + (size_t)row * EMB);
    u16* dst = E + (size_t)sb * EMB;
    const int t = threadIdx.x;             // 128 threads, 4 elems each
    floatx4 v = src[t];
    short4v o;
    o[0] = (short)f2bf(v[0]); o[1] = (short)f2bf(v[1]);
    o[2] = (short)f2bf(v[2]); o[3] = (short)f2bf(v[3]);
    *(short4v*)(dst + t * 4) = o;
}

// ---------------------------------------------------------------------------
// One LSTM time step, fused: gates = [Xt | hin] @ Wcat + b ; c,h update.
// Grid: 128 blocks x 256 thr. Block owns 32 gate columns = 8 hidden units.
// Waves k-split (round-robin 32-chunks), fp32 partials reduced through LDS.
// MFMA 16x16x32 frag layouts (verified m89/m91):
//   A: lane l -> A[l&15][(l>>4)*8 + j]   B: lane l -> B[(l>>4)*8 + j][l&15]
//   D: lane l, reg r -> D[(l>>4)*4 + r][l&15]
// ---------------------------------------------------------------------------
template<int K1, int NCH>
__global__ void __launch_bounds__(256) lstm_step(
    const u16* __restrict__ Xt,   // [64][K1]  (E_t or H_t)
    const u16* __restrict__ hin,  // [64][1024]
    u16* __restrict__ hout,       // [64][1024] (other buffer)
    u16* __restrict__ Hout,       // H[s] slice or nullptr
    float* __restrict__ cst,      // [64][1024] fp32 cell state
    const u16* __restrict__ W,    // packed [(K1+1024)/8][4096][8]
    const float* __restrict__ bfp, const float* __restrict__ bip,
    const float* __restrict__ bCp, const float* __restrict__ bop)
{
    __shared__ float red[4][64][33];
    const int tid = threadIdx.x;
    const int w = tid >> 6, l = tid & 63;
    const int ml = l & 15, q = l >> 4;
    const int n0 = blockIdx.x * 32;

    floatx4 acc[4][2];
#pragma unroll
    for (int mi = 0; mi < 4; ++mi)
#pragma unroll
        for (int ni = 0; ni < 2; ++ni)
            acc[mi][ni] = (floatx4){0.f, 0.f, 0.f, 0.f};

#pragma unroll 4
    for (int ci = 0; ci < NCH / 4; ++ci) {
        const int k = (ci * 4 + w) << 5;              // wave-uniform
        const u16* Ab; int lda, kl;
        if (k < K1) { Ab = Xt;  lda = K1;  kl = k; }
        else        { Ab = hin; lda = HID; kl = k - K1; }
        const u16* ar = Ab + (size_t)ml * lda + kl + q * 8;
        short8 a0 = *(const short8*)(ar);
        short8 a1 = *(const short8*)(ar + (size_t)16 * lda);
        short8 a2 = *(const short8*)(ar + (size_t)32 * lda);
        short8 a3 = *(const short8*)(ar + (size_t)48 * lda);
        const u16* br = W + ((size_t)((k >> 3) + q) * NG + n0 + ml) * 8;
        short8 b0 = *(const short8*)(br);
        short8 b1 = *(const short8*)(br + 16 * 8);
        acc[0][0] = __builtin_amdgcn_mfma_f32_16x16x32_bf16(a0, b0, acc[0][0], 0, 0, 0);
        acc[1][0] = __builtin_amdgcn_mfma_f32_16x16x32_bf16(a1, b0, acc[1][0], 0, 0, 0);
        acc[2][0] = __builtin_amdgcn_mfma_f32_16x16x32_bf16(a2, b0, acc[2][0], 0, 0, 0);
        acc[3][0] = __builtin_amdgcn_mfma_f32_16x16x32_bf16(a3, b0, acc[3][0], 0, 0, 0);
        acc[0][1] = __builtin_amdgcn_mfma_f32_16x16x32_bf16(a0, b1, acc[0][1], 0, 0, 0);
        acc[1][1] = __builtin_amdgcn_mfma_f32_16x16x32_bf16(a1, b1, acc[1][1], 0, 0, 0);
        acc[2][1] = __builtin_amdgcn_mfma_f32_16x16x32_bf16(a2, b1, acc[2][1], 0, 0, 0);
        acc[3][1] = __builtin_amdgcn_mfma_f32_16x16x32_bf16(a3, b1, acc[3][1], 0, 0, 0);
    }

#pragma unroll
    for (int mi = 0; mi < 4; ++mi)
#pragma unroll
        for (int ni = 0; ni < 2; ++ni)
#pragma unroll
            for (int r = 0; r < 4; ++r)
                red[w][mi * 16 + q * 4 + r][ni * 16 + ml] = acc[mi][ni][r];
    __syncthreads();

    const int m = tid >> 2;
#pragma unroll
    for (int hh = 0; hh < 2; ++hh) {
        const int u  = (tid & 3) + hh * 4;            // local unit 0..7
        const int ug = blockIdx.x * 8 + u;            // global unit
        const int nl = u * 4;
        float p0 = red[0][m][nl+0] + red[1][m][nl+0] + red[2][m][nl+0] + red[3][m][nl+0];
        float p1 = red[0][m][nl+1] + red[1][m][nl+1] + red[2][m][nl+1] + red[3][m][nl+1];
        float p2 = red[0][m][nl+2] + red[1][m][nl+2] + red[2][m][nl+2] + red[3][m][nl+2];
        float p3 = red[0][m][nl+3] + red[1][m][nl+3] + red[2][m][nl+3] + red[3][m][nl+3];
        float f = sigm(p0 + bfp[ug]);
        float i = sigm(p1 + bip[ug]);
        float g = tanhf(p2 + bCp[ug]);
        float o = sigm(p3 + bop[ug]);
        float c = f * cst[m * HID + ug] + i * g;
        cst[m * HID + ug] = c;
        u16 hb = f2bf(o * tanhf(c));
        hout[m * HID + ug] = hb;
        if (Hout) Hout[m * HID + ug] = hb;
    }
}

// out[64][10000] = h1 @ W_out + b_out   (314 blocks x 32 cols)
__global__ void __launch_bounds__(256) out_gemm(
    const u16* __restrict__ h1, const u16* __restrict__ W,
    const float* __restrict__ bout, float* __restrict__ out)
{
    __shared__ float red[4][64][33];
    const int tid = threadIdx.x;
    const int w = tid >> 6, l = tid & 63;
    const int ml = l & 15, q = l >> 4;
    const int n0 = blockIdx.x * 32;

    floatx4 acc[4][2];
#pragma unroll
    for (int mi = 0; mi < 4; ++mi)
#pragma unroll
        for (int ni = 0; ni < 2; ++ni)
            acc[mi][ni] = (floatx4){0.f, 0.f, 0.f, 0.f};

#pragma unroll
    for (int ci = 0; ci < 8; ++ci) {
        const int k = (ci * 4 + w) << 5;
        const u16* ar = h1 + (size_t)ml * HID + k + q * 8;
        short8 a0 = *(const short8*)(ar);
        short8 a1 = *(const short8*)(ar + 16 * HID);
        short8 a2 = *(const short8*)(ar + 32 * HID);
        short8 a3 = *(const short8*)(ar + 48 * HID);
        const u16* br = W + ((size_t)((k >> 3) + q) * NOP + n0 + ml) * 8;
        short8 b0 = *(const short8*)(br);
        short8 b1 = *(const short8*)(br + 16 * 8);
        acc[0][0] = __builtin_amdgcn_mfma_f32_16x16x32_bf16(a0, b0, acc[0][0], 0, 0, 0);
        acc[1][0] = __builtin_amdgcn_mfma_f32_16x16x32_bf16(a1, b0, acc[1][0], 0, 0, 0);
        acc[2][0] = __builtin_amdgcn_mfma_f32_16x16x32_bf16(a2, b0, acc[2][0], 0, 0, 0);
        acc[3][0] = __builtin_amdgcn_mfma_f32_16x16x32_bf16(a3, b0, acc[3][0], 0, 0, 0);
        acc[0][1] = __builtin_amdgcn_mfma_f32_16x16x32_bf16(a0, b1, acc[0][1], 0, 0, 0);
        acc[1][1] = __builtin_amdgcn_mfma_f32_16x16x32_bf16(a1, b1, acc[1][1], 0, 0, 0);
        acc[2][1] = __builtin_amdgcn_mfma_f32_16x16x32_bf16(a2, b1, acc[2][1], 0, 0, 0);
        acc[3][1] = __builtin_amdgcn_mfma_f32_16x16x32_bf16(a3, b1, acc[3][1], 0, 0, 0);
    }

#pragma unroll
    for (int mi = 0; mi < 4; ++mi)
#pragma unroll
        for (int ni = 0; ni < 2; ++ni)
#pragma unroll
            for (int r = 0; r < 4; ++r)
                red[w][mi * 16 + q * 4 + r][ni * 16 + ml] = acc[mi][ni][r];
    __syncthreads();

    const int m = tid >> 2;
#pragma unroll
    for (int jj = 0; jj < 8; ++jj) {
        const int nl = (tid & 3) * 8 + jj;
        const int n = n0 + nl;
        if (n < NCLS) {
            float v = red[0][m][nl] + red[1][m][nl] + red[2][m][nl] + red[3][m][nl] + bout[n];
            out[(size_t)m * NCLS + n] = v;
        }
    }
}

// ---------------------------------------------------------------------------
extern "C" void kernel_launch(void* const* d_in, const int* in_sizes, int n_in,
                              void* d_out, int out_size, void* d_ws, size_t ws_size,
                              hipStream_t stream) {
    const int*   X     = (const int*)  d_in[0];
    const float* C     = (const float*)d_in[1];
    const float* W_fx  = (const float*)d_in[2];
    const float* W_fh  = (const float*)d_in[3];
    const float* W_ix  = (const float*)d_in[4];
    const float* W_ih  = (const float*)d_in[5];
    const float* W_Cx  = (const float*)d_in[6];
    const float* W_Ch  = (const float*)d_in[7];
    const float* W_ox  = (const float*)d_in[8];
    const float* W_oh  = (const float*)d_in[9];
    const float* W_fx1 = (const float*)d_in[10];
    const float* W_fh1 = (const float*)d_in[11];
    const float* W_ix1 = (const float*)d_in[12];
    // d_in[13] = W_ih1 — unused: reference reuses W_ih in layer-1 i-gate (bug kept)
    const float* W_Cx1 = (const float*)d_in[14];
    const float* W_Ch1 = (const float*)d_in[15];
    const float* W_ox1 = (const float*)d_in[16];
    const float* W_oh1 = (const float*)d_in[17];
    const float* W_out = (const float*)d_in[18];
    const float* b_f   = (const float*)d_in[19];
    const float* b_i   = (const float*)d_in[20];
    const float* b_C   = (const float*)d_in[21];
    const float* b_o   = (const float*)d_in[22];
    const float* b_f1  = (const float*)d_in[23];
    const float* b_i1  = (const float*)d_in[24];
    const float* b_C1  = (const float*)d_in[25];
    const float* b_o1  = (const float*)d_in[26];
    const float* b_out = (const float*)d_in[27];
    float* out = (float*)d_out;

    // workspace carve (all sizes multiples of 256 B)
    uint8_t* ws = (uint8_t*)d_ws;
    const size_t SZ_WCAT0 = (size_t)1536 * NG * 2;    // 12 MB
    const size_t SZ_WCAT1 = (size_t)2048 * NG * 2;    // 16 MB
    const size_t SZ_WOUTP = (size_t)1024 * NOP * 2;   // ~20 MB
    const size_t SZ_E     = (size_t)SEQ * BATCH * EMB * 2;   // 8 MB
    const size_t SZ_H     = (size_t)SEQ * BATCH * HID * 2;   // 16 MB
    const size_t SZ_HB    = (size_t)BATCH * HID * 2;         // 128 KB
    const size_t SZ_C     = (size_t)BATCH * HID * 4;         // 256 KB
    u16*   Wcat0 = (u16*)ws;                         ws += SZ_WCAT0;
    u16*   Wcat1 = (u16*)ws;                         ws += SZ_WCAT1;
    u16*   WoutP = (u16*)ws;                         ws += SZ_WOUTP;
    u16*   E     = (u16*)ws;                         ws += SZ_E;
    u16*   H     = (u16*)ws;                         ws += SZ_H;
    u16*   h0a   = (u16*)ws;                         ws += SZ_HB;
    u16*   h0b   = (u16*)ws;                         ws += SZ_HB;
    u16*   h1a   = (u16*)ws;                         ws += SZ_HB;
    u16*   h1b   = (u16*)ws;                         ws += SZ_HB;
    float* cst   = (float*)ws;                       ws += SZ_C;

    // --- pack weights (per call: harness restores inputs each timed launch)
    pack_gates<<<256, 256, 0, stream>>>(W_fx, W_ix, W_Cx, W_ox, Wcat0, 64, 0);
    pack_gates<<<512, 256, 0, stream>>>(W_fh, W_ih, W_Ch, W_oh, Wcat0, 128, 64);
    pack_gates<<<512, 256, 0, stream>>>(W_fx1, W_ix1, W_Cx1, W_ox1, Wcat1, 128, 0);
    pack_gates<<<512, 256, 0, stream>>>(W_fh1, W_ih, W_Ch1, W_oh1, Wcat1, 128, 128);
    hipMemsetAsync(WoutP, 0, SZ_WOUTP, stream);
    pack_wout<<<(128 * NCLS + 255) / 256, 256, 0, stream>>>(W_out, WoutP);
    embed_k<<<SEQ * BATCH, 128, 0, stream>>>(X, C, E);

    // --- layer 0: gates = [E_t | h] @ Wcat0 + b   (K = 512 + 1024, 48 chunks)
    hipMemsetAsync(h0a, 0, SZ_HB, stream);
    hipMemsetAsync(cst, 0, SZ_C, stream);
    for (int s = 0; s < SEQ; ++s) {
        const u16* hin = (s & 1) ? h0b : h0a;
        u16*       ho  = (s & 1) ? h0a : h0b;
        lstm_step<512, 48><<<128, 256, 0, stream>>>(
            E + (size_t)s * BATCH * EMB, hin, ho, H + (size_t)s * BATCH * HID,
            cst, Wcat0, b_f, b_i, b_C, b_o);
    }

    // --- layer 1: gates = [H_t | h1] @ Wcat1 + b  (K = 1024 + 1024, 64 chunks)
    hipMemsetAsync(h1a, 0, SZ_HB, stream);
    hipMemsetAsync(cst, 0, SZ_C, stream);
    for (int s = 0; s < SEQ; ++s) {
        const u16* hin = (s & 1) ? h1b : h1a;
        u16*       ho  = (s & 1) ? h1a : h1b;
        lstm_step<1024, 64><<<128, 256, 0, stream>>>(
            H + (size_t)s * BATCH * HID, hin, ho, nullptr,
            cst, Wcat1, b_f1, b_i1, b_C1, b_o1);
    }

    // --- output projection (final h1 ends in h1a after 128 steps)
    out_gemm<<<314, 256, 0, stream>>>(h1a, WoutP, b_out, out);
}